// Round 6
// baseline (1117.738 us; speedup 1.0000x reference)
//
#include <hip/hip_runtime.h>
#include <stdint.h>

typedef __bf16 bf16;
typedef __bf16 bf16x8 __attribute__((ext_vector_type(8)));
typedef float f32x4 __attribute__((ext_vector_type(4)));

#define DEV __device__ __forceinline__

static constexpr int Dm   = 1024;
static constexpr int DFFm = 4096;
static constexpr int Tm   = 2048;   // B*S tokens
static constexpr int Vm   = 32000;

// ---------------- helpers ----------------
#define GLOAD_LDS16(g, l)                                                      \
  __builtin_amdgcn_global_load_lds(                                            \
      (const __attribute__((address_space(1))) unsigned int*)(g),              \
      (__attribute__((address_space(3))) unsigned int*)(l), 16, 0, 0)

DEV float gelu_tanh(float v) {  // matches jax.nn.gelu (approximate=True)
  float u = 0.7978845608028654f * (v + 0.044715f * v * v * v);
  float e = __expf(2.0f * u);
  float t = 1.0f - 2.0f / (e + 1.0f);
  return 0.5f * v * (1.0f + t);
}

// =======================================================================
// 256x256-tile / 8-wave / 4-phase counted-vmcnt GEMM: C = A[M][K]·B^T + b
// LDS: 2 buf x [Akh0|Bkh0|Akh1|Bkh1], each slot [128 super-rows][128B].
// Swizzle: 16B-slot s of super-row sr holds (row 2sr+(v>>2), chunk v&3),
// v = s ^ (sr&7)  -> conflict-free ds_read_b128 AND linear gload dests.
// k-wrap remap (aT/aS2, bT/bS2) lets [h|l] storage serve [h|l|h]-style
// augmented-K operands without duplication.
// =======================================================================
struct G256P {
  const bf16* A; const bf16* B;
  const float* bias;
  float* outF;
  int K;               // K per z-chunk
  int N;
  int lda; int ldb;
  int kcK;             // k offset per blockIdx.z
  int aT, aS2, bT, bS2;  // if (k >= T) k -= S2
};

template <int EPI /*0=store+bias, 1=atomicAdd(+bias at kc0)*/, bool SWZ>
__launch_bounds__(512, 2)
__global__ void gemm256(G256P p) {
  __shared__ bf16 lds[65536];   // 128 KiB
  const int tid  = threadIdx.x;
  const int lane = tid & 63;
  const int wid  = tid >> 6;    // 8 waves: 2 (wr) x 4 (wc); wave out 128x64
  const int wr   = wid >> 2;
  const int wc   = wid & 3;
  const int kc   = blockIdx.z;

  int bx = blockIdx.x, by = blockIdx.y;
  if constexpr (SWZ) {
    const int gx = gridDim.x, gy = gridDim.y;
    const int nwg = gx * gy;
    const int lin = by * gx + bx;
    const int q = nwg >> 3, r = nwg & 7;
    const int xcd = lin & 7, loc = lin >> 3;
    const int nid = (xcd < r ? xcd * (q + 1) : r * (q + 1) + (xcd - r) * q) + loc;
    bx = nid / gy; by = nid % gy;
  }
  const long am0 = (long)by * 256;
  const long bn0 = (long)bx * 256;
  const long lda = p.lda, ldb = p.ldb;
  const int kco = kc * p.kcK;
  const int NT = p.K >> 6;

  // ---- staging source pointers (pre-swizzled global, linear LDS dest) ----
  const int v = (lane & 7) ^ (lane >> 3);
  const long arow = 2 * (wid * 8 + (lane >> 3)) + (v >> 2);
  const bf16* aR0 = p.A + (am0 + arow) * lda + (v & 3) * 8;
  const bf16* aR1 = aR0 + 128 * lda;
  const bf16* bR0 = p.B + (bn0 + arow) * ldb + (v & 3) * 8;
  const bf16* bR1 = bR0 + 128 * ldb;
  char* ldsc = (char*)(void*)lds;

  auto stageA = [&](int kt, int kh) {   // 2 loads: A k-half slot of tile kt
    const int ku = kco + kt * 64 + kh * 32;
    const long ka = (ku >= p.aT) ? ku - p.aS2 : ku;
    char* d = ldsc + (kt & 1) * 65536 + kh * 32768 + wid * 1024;  // +lane*16 HW
    GLOAD_LDS16(aR0 + ka, d);
    GLOAD_LDS16(aR1 + ka, d + 8192);
  };
  auto stageB = [&](int kt, int kh) {
    const int ku = kco + kt * 64 + kh * 32;
    const long kb = (ku >= p.bT) ? ku - p.bS2 : ku;
    char* d = ldsc + (kt & 1) * 65536 + kh * 32768 + 16384 + wid * 1024;
    GLOAD_LDS16(bR0 + kb, d);
    GLOAD_LDS16(bR1 + kb, d + 8192);
  };

  f32x4 acc[8][4] = {};
  const int r15 = lane & 15;
  const int kcs = lane >> 4;
  // per-lane base byte offset inside a slot (swizzled read address)
  const int boff = (r15 >> 1) * 128 +
                   (((((r15 & 1) << 2) | kcs) ^ ((r15 >> 1) & 7)) << 4);

  // prologue: tiles 0 and 1 fully staged (issue order defines vmcnt gates)
  stageA(0, 0); stageB(0, 0); stageA(0, 1); stageB(0, 1);
  stageA(1, 0); stageB(1, 0); stageA(1, 1); stageB(1, 1);

  for (int t = 0; t < NT; ++t) {
    const char* buf = ldsc + (t & 1) * 65536;
    const bool st = (t >= 1) && (t + 1 < NT);

    // ---------------- k-half 0 ----------------
    if (t == 0) asm volatile("s_waitcnt vmcnt(12)" ::: "memory");
    else        asm volatile("s_waitcnt vmcnt(4)" ::: "memory");
    __builtin_amdgcn_s_barrier();
    {
      const char* Ab = buf + boff + wr * 8192;
      const char* Bb = buf + 16384 + boff + wc * 4096;
      bf16x8 a[4], b[4];
#pragma unroll
      for (int n = 0; n < 4; ++n) b[n] = *(const bf16x8*)(Bb + n * 1024);
#pragma unroll
      for (int m = 0; m < 4; ++m) a[m] = *(const bf16x8*)(Ab + m * 1024);
      if (st) stageA(t + 1, 0);
      __builtin_amdgcn_s_setprio(1);
#pragma unroll
      for (int m = 0; m < 4; ++m)
#pragma unroll
        for (int n = 0; n < 4; ++n)
          acc[m][n] = __builtin_amdgcn_mfma_f32_16x16x32_bf16(a[m], b[n], acc[m][n], 0, 0, 0);
      __builtin_amdgcn_s_setprio(0);
#pragma unroll
      for (int m = 0; m < 4; ++m) a[m] = *(const bf16x8*)(Ab + 4096 + m * 1024);
      if (st) stageB(t + 1, 0);
      __builtin_amdgcn_s_setprio(1);
#pragma unroll
      for (int m = 0; m < 4; ++m)
#pragma unroll
        for (int n = 0; n < 4; ++n)
          acc[4 + m][n] = __builtin_amdgcn_mfma_f32_16x16x32_bf16(a[m], b[n], acc[4 + m][n], 0, 0, 0);
      __builtin_amdgcn_s_setprio(0);
    }

    // ---------------- k-half 1 ----------------
    if (t == 0)           asm volatile("s_waitcnt vmcnt(8)" ::: "memory");
    else if (t == NT - 1) asm volatile("s_waitcnt vmcnt(0)" ::: "memory");
    else                  asm volatile("s_waitcnt vmcnt(4)" ::: "memory");
    __builtin_amdgcn_s_barrier();
    {
      const char* Ab = buf + 32768 + boff + wr * 8192;
      const char* Bb = buf + 32768 + 16384 + boff + wc * 4096;
      bf16x8 a[4], b[4];
#pragma unroll
      for (int n = 0; n < 4; ++n) b[n] = *(const bf16x8*)(Bb + n * 1024);
#pragma unroll
      for (int m = 0; m < 4; ++m) a[m] = *(const bf16x8*)(Ab + m * 1024);
      if (st) stageA(t + 1, 1);
      __builtin_amdgcn_s_setprio(1);
#pragma unroll
      for (int m = 0; m < 4; ++m)
#pragma unroll
        for (int n = 0; n < 4; ++n)
          acc[m][n] = __builtin_amdgcn_mfma_f32_16x16x32_bf16(a[m], b[n], acc[m][n], 0, 0, 0);
      __builtin_amdgcn_s_setprio(0);
#pragma unroll
      for (int m = 0; m < 4; ++m) a[m] = *(const bf16x8*)(Ab + 4096 + m * 1024);
      if (st) stageB(t + 1, 1);
      __builtin_amdgcn_s_setprio(1);
#pragma unroll
      for (int m = 0; m < 4; ++m)
#pragma unroll
        for (int n = 0; n < 4; ++n)
          acc[4 + m][n] = __builtin_amdgcn_mfma_f32_16x16x32_bf16(a[m], b[n], acc[4 + m][n], 0, 0, 0);
      __builtin_amdgcn_s_setprio(0);
    }
  }

  const long N = p.N;
#pragma unroll
  for (int m = 0; m < 8; ++m) {
#pragma unroll
    for (int n = 0; n < 4; ++n) {
      const long col = bn0 + wc * 64 + n * 16 + r15;
      const float bv = (EPI == 0 || kc == 0) ? p.bias[col] : 0.0f;
#pragma unroll
      for (int r = 0; r < 4; ++r) {
        const long row = am0 + wr * 128 + m * 16 + (lane >> 4) * 4 + r;
        if constexpr (EPI == 0) {
          p.outF[row * N + col] = acc[m][n][r] + bv;
        } else {
          atomicAdd(p.outF + row * N + col, acc[m][n][r] + bv);
        }
      }
    }
  }
}

// ---------------- 128^2 GEMM (experts): unchanged verified structure ------
enum { EPI_GELU_BF16 = 2, EPI_MOE = 3 };

struct GemmP {
  const bf16* Ah;
  const bf16* Bh;
  const float* bias;
  const float* rwp;
  const int* cnt;
  const int* idx;
  float* outF;
  bf16* outH;
  int K; int N;
  int lda; int ldb;
  long aBS, bBS, outBS;
  int biasBS;
  int ebase;
  int kcShift; int kcK;
};

template <int EPI, bool GATHER, bool SWZ>
__launch_bounds__(256, 2)
__global__ void gemm_bt(GemmP p) {
  __shared__ bf16 lds[16384];
  bf16* ldsA = lds;
  bf16* ldsB = lds + 8192;

  const int tid  = threadIdx.x;
  const int lane = tid & 63;
  const int wid  = tid >> 6;
  const int wr   = wid >> 1;
  const int wc   = wid & 1;
  const int z    = blockIdx.z;
  const int kc   = z & ((1 << p.kcShift) - 1);
  const int ze   = z >> p.kcShift;

  int bx = blockIdx.x, by = blockIdx.y;
  if constexpr (SWZ) {
    const int gx = gridDim.x, gy = gridDim.y;
    const int nwg = gx * gy;
    const int lin = by * gx + bx;
    const int q = nwg >> 3, r = nwg & 7;
    const int xcd = lin & 7, loc = lin >> 3;
    const int nid = (xcd < r ? xcd * (q + 1) : r * (q + 1) + (xcd - r) * q) + loc;
    bx = nid / gy; by = nid % gy;
  }

  const long am0 = (long)by * 128;
  const long bn0 = (long)bx * 128;

  int cntE = 0;
  const int* il = nullptr;
  if constexpr (GATHER || EPI == EPI_MOE) {
    cntE = p.cnt[p.ebase + ze];
    if (am0 >= cntE) return;
    il = p.idx + (long)(p.ebase + ze) * 2048;
  }

  const long lda = p.lda, ldb = p.ldb;
  const long K = p.K;
  const long kco = (long)kc * p.kcK;

  const int sub = (lane & 7) ^ (lane >> 3);
  const int rIn = wid * 8 + (lane >> 3);

  const bf16 *aS[4], *bS[4];
  {
    const bf16* Bb = p.Bh + (long)ze * p.bBS + kco + bn0 * ldb;
    const bf16* Ab = p.Ah + (long)ze * p.aBS + kco + am0 * lda;
#pragma unroll
    for (int j = 0; j < 4; ++j) {
      const int row = j * 32 + rIn;
      bS[j] = Bb + (long)row * ldb + sub * 8;
      if constexpr (GATHER) {
        const int rt = (int)am0 + row;
        const long grow = il[rt < cntE ? rt : 0];
        aS[j] = p.Ah + grow * lda + kco + sub * 8;
      } else {
        aS[j] = Ab + (long)row * lda + sub * 8;
      }
    }
  }
  char* dstA[4];
#pragma unroll
  for (int j = 0; j < 4; ++j)
    dstA[j] = (char*)(void*)lds + (j * 256 + wid * 64) * 16;

  f32x4 acc[4][4] = {};

  const int r15 = lane & 15;
  const int kcs = lane >> 4;
  const int xk  = lane & 7;

  for (long k0 = 0; k0 < K; k0 += 64) {
    __syncthreads();
#pragma unroll
    for (int j = 0; j < 4; ++j) {
      GLOAD_LDS16(aS[j] + k0, dstA[j]);
      GLOAD_LDS16(bS[j] + k0, dstA[j] + 16384);
    }
    __syncthreads();
#pragma unroll
    for (int h = 0; h < 2; ++h) {
      const int q8 = ((kcs + 4 * h) ^ xk) << 3;
      bf16x8 a[4], b[4];
#pragma unroll
      for (int m = 0; m < 4; ++m)
        a[m] = *(const bf16x8*)(ldsA + (wr * 64 + m * 16 + r15) * 64 + q8);
#pragma unroll
      for (int n = 0; n < 4; ++n)
        b[n] = *(const bf16x8*)(ldsB + (wc * 64 + n * 16 + r15) * 64 + q8);
#pragma unroll
      for (int m = 0; m < 4; ++m)
#pragma unroll
        for (int n = 0; n < 4; ++n)
          acc[m][n] = __builtin_amdgcn_mfma_f32_16x16x32_bf16(a[m], b[n], acc[m][n], 0, 0, 0);
    }
  }

  const long N = p.N;
#pragma unroll
  for (int m = 0; m < 4; ++m) {
#pragma unroll
    for (int n = 0; n < 4; ++n) {
      const long col = bn0 + wc * 64 + n * 16 + (lane & 15);
      const float bv = (kc == 0) ? p.bias[(long)ze * p.biasBS + col] : 0.0f;
#pragma unroll
      for (int r = 0; r < 4; ++r) {
        const long row = am0 + wr * 64 + m * 16 + (lane >> 4) * 4 + r;
        float v = acc[m][n][r] + bv;
        if constexpr (EPI == EPI_GELU_BF16) {
          long o = (long)ze * p.outBS + row * N + col;
          p.outH[o] = (bf16)gelu_tanh(v);
        } else {  // EPI_MOE
          if (row < cntE) {
            const int tok = il[row];
            const float wgt = p.rwp[(long)tok * 8 + p.ebase + ze];
            atomicAdd(p.outF + (long)tok * N + col, wgt * v);
          }
        }
      }
    }
  }
}

// ------- transpose fp32 [R][C] -> bf16 [C][R] (AUG2: [C][2R] = [h|l]) -------
template <bool AUG2>
__global__ void transpose_cvt(const float* __restrict__ in, bf16* __restrict__ out,
                              int R, int C, long inBS, long outBS) {
  __shared__ float tile[32][33];
  const float* inp = in + (long)blockIdx.z * inBS;
  const long c0 = (long)blockIdx.x * 32;
  const long r0 = (long)blockIdx.y * 32;
  const int tx = threadIdx.x;  // 32
  const int ty = threadIdx.y;  // 8
#pragma unroll
  for (int i = 0; i < 4; ++i) {
    int r = ty + i * 8;
    tile[r][tx] = inp[(r0 + r) * (long)C + c0 + tx];
  }
  __syncthreads();
  const long ob = (long)blockIdx.z * outBS;
  const long stride = AUG2 ? 2L * R : (long)R;
#pragma unroll
  for (int i = 0; i < 4; ++i) {
    int c = ty + i * 8;
    float v = tile[tx][c];
    bf16 h = (bf16)v;
    long o = ob + (c0 + c) * stride + r0 + tx;
    out[o] = h;
    if constexpr (AUG2) out[o + R] = (bf16)(v - (float)h);
  }
}

// ------------- embedding gather -------------
__global__ void embed_kernel(const int* __restrict__ ids, const float* __restrict__ emb,
                             float* __restrict__ x) {
  const long t = blockIdx.x;
  const int id = ids[t];
  ((float4*)(x + t * 1024))[threadIdx.x] = ((const float4*)(emb + (long)id * 1024))[threadIdx.x];
}

// ------------- LayerNorm -> bf16 [h|l] row (stride 2048) -------------
__global__ void ln_aug2_kernel(const float* __restrict__ x, const float* __restrict__ sc,
                               const float* __restrict__ bi, bf16* __restrict__ oa) {
  const long t = blockIdx.x;
  const int tid = threadIdx.x;  // 256
  const int lane = tid & 63, wid = tid >> 6;
  float4 a = ((const float4*)(x + t * 1024))[tid];
  float s = a.x + a.y + a.z + a.w;
  float q = a.x * a.x + a.y * a.y + a.z * a.z + a.w * a.w;
#pragma unroll
  for (int off = 32; off; off >>= 1) {
    s += __shfl_down(s, off);
    q += __shfl_down(q, off);
  }
  __shared__ float sr[4], qr[4];
  if (lane == 0) { sr[wid] = s; qr[wid] = q; }
  __syncthreads();
  s = sr[0] + sr[1] + sr[2] + sr[3];
  q = qr[0] + qr[1] + qr[2] + qr[3];
  const float mu = s * (1.0f / 1024.0f);
  const float var = q * (1.0f / 1024.0f) - mu * mu;
  const float rs = rsqrtf(var + 1e-5f);
#pragma unroll
  for (int j = 0; j < 4; ++j) {
    const int d = tid * 4 + j;
    const float g = (((const float*)&a)[j] - mu) * rs * sc[d] + bi[d];
    const bf16 h = (bf16)g;
    oa[t * 2048 + d] = h;
    oa[t * 2048 + 1024 + d] = (bf16)(g - (float)h);
  }
}

// ------------- gelu + hi/lo split: Z fp32 [2048][4096] -> H [2048][8192] ----
__global__ void gelu_aug2_kernel(const float* __restrict__ Z, bf16* __restrict__ H) {
  const long i8 = ((long)blockIdx.x * 256 + threadIdx.x) * 8;
  const long r = i8 >> 12, c = i8 & 4095;
  float4 a = *(const float4*)(Z + i8);
  float4 b = *(const float4*)(Z + i8 + 4);
  bf16x8 h, l;
#pragma unroll
  for (int j = 0; j < 8; ++j) {
    float g = gelu_tanh(j < 4 ? ((const float*)&a)[j] : ((const float*)&b)[j - 4]);
    bf16 hh = (bf16)g;
    h[j] = hh;
    l[j] = (bf16)(g - (float)hh);
  }
  *(bf16x8*)(H + r * 8192 + c) = h;
  *(bf16x8*)(H + r * 8192 + 4096 + c) = l;
}

// ------------- router: logits, top-2 softmax, scatter + top2 record -------------
__global__ void router_kernel(const float* __restrict__ x, const float* __restrict__ Wr,
                              const float* __restrict__ br, float* __restrict__ rwo,
                              int* __restrict__ top2) {
  const long t = blockIdx.x;
  const int lane = threadIdx.x;  // 64
  float acc[8];
#pragma unroll
  for (int e = 0; e < 8; ++e) acc[e] = 0.0f;
  const float4* xr = (const float4*)(x + t * 1024);
#pragma unroll
  for (int j = 0; j < 4; ++j) {
    const int d4 = j * 64 + lane;
    float4 xv = xr[d4];
#pragma unroll
    for (int u = 0; u < 4; ++u) {
      const float xs = ((const float*)&xv)[u];
      const float4* wp = (const float4*)(Wr + (long)(d4 * 4 + u) * 8);
      float4 w0 = wp[0], w1 = wp[1];
      acc[0] += xs * w0.x; acc[1] += xs * w0.y; acc[2] += xs * w0.z; acc[3] += xs * w0.w;
      acc[4] += xs * w1.x; acc[5] += xs * w1.y; acc[6] += xs * w1.z; acc[7] += xs * w1.w;
    }
  }
#pragma unroll
  for (int off = 32; off; off >>= 1)
#pragma unroll
    for (int e = 0; e < 8; ++e) acc[e] += __shfl_down(acc[e], off);
  if (lane == 0) {
    float v[8];
#pragma unroll
    for (int e = 0; e < 8; ++e) v[e] = acc[e] + br[e];
    int i0 = 0; float v0 = v[0];
    for (int e = 1; e < 8; ++e) if (v[e] > v0) { v0 = v[e]; i0 = e; }
    int i1 = -1; float v1 = -3.4e38f;
    for (int e = 0; e < 8; ++e) if (e != i0 && v[e] > v1) { v1 = v[e]; i1 = e; }
    float e1 = expf(v1 - v0);
    float den = 1.0f + e1;
    float w0 = 1.0f / den, w1 = e1 / den;
    float* o = rwo + t * 8;
#pragma unroll
    for (int e = 0; e < 8; ++e) o[e] = (e == i0) ? w0 : (e == i1 ? w1 : 0.0f);
    top2[t] = i0 | (i1 << 8);
  }
}

// ------------- per-expert token list build -------------
__global__ void build_lists(const int* __restrict__ top2, int* __restrict__ cnt,
                            int* __restrict__ idx) {
  const int t = blockIdx.x * 256 + threadIdx.x;
  const int rec = top2[t];
  const int e0 = rec & 255, e1 = (rec >> 8) & 255;
  int p0 = atomicAdd(&cnt[e0], 1);
  idx[e0 * 2048 + p0] = t;
  int p1 = atomicAdd(&cnt[e1], 1);
  idx[e1 * 2048 + p1] = t;
}

// ------------- fp32 -> bf16 flat convert -------------
__global__ void cvt_bf16_kernel(const float* __restrict__ in, bf16* __restrict__ out, long n) {
  long i = ((long)blockIdx.x * blockDim.x + threadIdx.x) * 8;
  if (i >= n) return;
  float4 a = *(const float4*)(in + i);
  float4 b = *(const float4*)(in + i + 4);
  bf16x8 o;
  o[0] = (bf16)a.x; o[1] = (bf16)a.y; o[2] = (bf16)a.z; o[3] = (bf16)a.w;
  o[4] = (bf16)b.x; o[5] = (bf16)b.y; o[6] = (bf16)b.z; o[7] = (bf16)b.w;
  *(bf16x8*)(out + i) = o;
}

// ---------------- host launch ----------------
extern "C" void kernel_launch(void* const* d_in, const int* in_sizes, int n_in,
                              void* d_out, int out_size, void* d_ws, size_t ws_size,
                              hipStream_t stream) {
  (void)in_sizes; (void)n_in; (void)out_size; (void)ws_size;
  const int*   ids  = (const int*)d_in[0];
  const float* emb  = (const float*)d_in[1];
  const float* tlns = (const float*)d_in[2];
  const float* tlnb = (const float*)d_in[3];
  const float* tw1  = (const float*)d_in[4];
  const float* tb1  = (const float*)d_in[5];
  const float* tw2  = (const float*)d_in[6];
  const float* tb2  = (const float*)d_in[7];
  const float* Wr   = (const float*)d_in[8];
  const float* br   = (const float*)d_in[9];
  const float* ew1  = (const float*)d_in[10];
  const float* eb1  = (const float*)d_in[11];
  const float* ew2  = (const float*)d_in[12];
  const float* eb2  = (const float*)d_in[13];
  const float* Wl   = (const float*)d_in[14];
  const float* bl   = (const float*)d_in[15];

  float* logits = (float*)d_out;
  float* rwout  = (float*)d_out + (long)Tm * Vm;

  size_t off = 0;
  auto take = [&](size_t bytes) {
    void* pp = (char*)d_ws + off;
    off += (bytes + 255) & ~(size_t)255;
    return pp;
  };
  float* X    = (float*)take((size_t)Tm * Dm * 4);
  bf16*  XB   = (bf16*) take((size_t)Tm * Dm * 2);
  float* Y    = (float*)take((size_t)Tm * Dm * 4);
  bf16*  YB   = (bf16*) take((size_t)Tm * Dm * 2);
  int*   top2 = (int*)  take((size_t)Tm * 4);
  int*   cnt  = (int*)  take(8 * 4);
  int*   idxl = (int*)  take((size_t)8 * Tm * 4);
  char*  S    = (char*) take(134217728);   // 128 MiB phase-shared scratch

  // temporal phase ([h|l] compressed aug layout)
  bf16*  A1  = (bf16*)S;                         // [2048][2048]   8.4 MB
  bf16*  W1A = (bf16*)(S + 8388608);             // [4096][2048]  16.8 MB
  bf16*  W2A = (bf16*)(S + 25165824);            // [1024][8192]  16.8 MB
  float* Z   = (float*)(S + 41943040);           // [2048][4096]  33.6 MB
  bf16*  HTA = (bf16*)(S + 75497472);            // [2048][8192]  33.6 MB (end 109.1)
  // expert phase
  bf16* EW1T = (bf16*)S;                         // 4x[4096][1024] 33.6 MB
  bf16* HE   = (bf16*)(S + 33554432);            // 4x[2048][4096] 67.1 MB
  bf16* EW2T = (bf16*)(S + 100663296);           // 4x[1024][4096] 33.6 MB
  // logits phase
  bf16* WLT  = (bf16*)S;                         // [32000][1024]  65.5 MB

  embed_kernel<<<dim3(Tm), dim3(256), 0, stream>>>(ids, emb, X);

  // ---- temporal residual MLP blocks: 256^2 pipelined GEMMs, split-K ----
  for (int l = 0; l < 2; ++l) {
    transpose_cvt<true><<<dim3(DFFm / 32, Dm / 32, 1), dim3(32, 8), 0, stream>>>(
        tw1 + (long)l * Dm * DFFm, W1A, Dm, DFFm, 0, 0);
    transpose_cvt<true><<<dim3(Dm / 32, DFFm / 32, 1), dim3(32, 8), 0, stream>>>(
        tw2 + (long)l * DFFm * Dm, W2A, DFFm, Dm, 0, 0);
    ln_aug2_kernel<<<dim3(Tm), dim3(256), 0, stream>>>(X, tlns + l * Dm, tlnb + l * Dm, A1);
    hipMemsetAsync(Z, 0, (size_t)Tm * DFFm * 4, stream);

    // Z = A1_aug([h|l|h]) x W1_aug([h|h|l])^T + b1   (K=3072, split-K 2)
    G256P p1{};
    p1.A = A1; p1.B = W1A; p1.bias = tb1 + (long)l * DFFm; p1.outF = Z;
    p1.K = 1536; p1.N = DFFm; p1.lda = 2048; p1.ldb = 2048; p1.kcK = 1536;
    p1.aT = 2048; p1.aS2 = 2048; p1.bT = 1024; p1.bS2 = 1024;
    gemm256<1, true><<<dim3(DFFm / 256, Tm / 256, 2), dim3(512), 0, stream>>>(p1);

    gelu_aug2_kernel<<<dim3(Tm * DFFm / (256 * 8)), dim3(256), 0, stream>>>(Z, HTA);

    // X += HTA_aug([h|l|h]) x W2_aug([h|h|l])^T + b2   (K=12288, split-K 8)
    G256P p2{};
    p2.A = HTA; p2.B = W2A; p2.bias = tb2 + (long)l * Dm; p2.outF = X;
    p2.K = 1536; p2.N = Dm; p2.lda = 8192; p2.ldb = 8192; p2.kcK = 1536;
    p2.aT = 8192; p2.aS2 = 8192; p2.bT = 4096; p2.bS2 = 4096;
    gemm256<1, true><<<dim3(Dm / 256, Tm / 256, 8), dim3(512), 0, stream>>>(p2);
  }

  // ---- router (fp32) + token lists ----
  router_kernel<<<dim3(Tm), dim3(64), 0, stream>>>(X, Wr, br, rwout, top2);
  hipMemsetAsync(cnt, 0, 8 * 4, stream);
  build_lists<<<dim3(Tm / 256), dim3(256), 0, stream>>>(top2, cnt, idxl);
  cvt_bf16_kernel<<<dim3(Tm * Dm / (256 * 8)), dim3(256), 0, stream>>>(X, XB, (long)Tm * Dm);
  hipMemsetAsync(Y, 0, (size_t)Tm * Dm * 4, stream);

  // ---- sparse top-2 expert stack, 2 quads of 4 experts (bf16, 128^2) ----
  for (int q = 0; q < 2; ++q) {
    transpose_cvt<false><<<dim3(DFFm / 32, Dm / 32, 4), dim3(32, 8), 0, stream>>>(
        ew1 + (long)q * 4 * Dm * DFFm, EW1T, Dm, DFFm, (long)Dm * DFFm, (long)DFFm * Dm);
    transpose_cvt<false><<<dim3(Dm / 32, DFFm / 32, 4), dim3(32, 8), 0, stream>>>(
        ew2 + (long)q * 4 * DFFm * Dm, EW2T, DFFm, Dm, (long)DFFm * Dm, (long)Dm * DFFm);

    GemmP pe1{};
    pe1.Ah = XB; pe1.Bh = EW1T;
    pe1.bias = eb1 + (long)q * 4 * DFFm; pe1.biasBS = DFFm;
    pe1.outH = HE; pe1.outBS = (long)Tm * DFFm;
    pe1.aBS = 0; pe1.bBS = (long)DFFm * Dm;
    pe1.cnt = cnt; pe1.idx = idxl; pe1.ebase = q * 4;
    pe1.K = Dm; pe1.N = DFFm; pe1.lda = Dm; pe1.ldb = Dm;
    gemm_bt<EPI_GELU_BF16, true, true>
        <<<dim3(DFFm / 128, Tm / 128, 4), dim3(256), 0, stream>>>(pe1);

    GemmP pe2{};
    pe2.Ah = HE; pe2.aBS = (long)Tm * DFFm;
    pe2.Bh = EW2T; pe2.bBS = (long)Dm * DFFm;
    pe2.bias = eb2 + (long)q * 4 * Dm; pe2.biasBS = Dm;
    pe2.rwp = rwout; pe2.cnt = cnt; pe2.idx = idxl; pe2.ebase = q * 4;
    pe2.outF = Y;
    pe2.K = 1024; pe2.N = Dm; pe2.lda = DFFm; pe2.ldb = DFFm;
    pe2.kcShift = 2; pe2.kcK = 1024;
    gemm_bt<EPI_MOE, false, true>
        <<<dim3(Dm / 128, Tm / 128, 16), dim3(256), 0, stream>>>(pe2);
  }

  // ---- final logits GEMM (256^2 pipelined) ----
  cvt_bf16_kernel<<<dim3(Tm * Dm / (256 * 8)), dim3(256), 0, stream>>>(Y, YB, (long)Tm * Dm);
  transpose_cvt<false><<<dim3(Vm / 32, Dm / 32, 1), dim3(32, 8), 0, stream>>>(
      Wl, WLT, Dm, Vm, 0, 0);
  G256P pl{};
  pl.A = YB; pl.B = WLT; pl.bias = bl; pl.outF = logits;
  pl.K = Dm; pl.N = Vm; pl.lda = Dm; pl.ldb = Dm; pl.kcK = 0;
  pl.aT = 1 << 30; pl.aS2 = 0; pl.bT = 1 << 30; pl.bS2 = 0;
  gemm256<0, true><<<dim3(Vm / 256, Tm / 256, 1), dim3(512), 0, stream>>>(pl);
}

// Round 7
// 979.698 us; speedup vs baseline: 1.1409x; 1.1409x over previous
//
#include <hip/hip_runtime.h>
#include <stdint.h>

typedef __bf16 bf16;
typedef __bf16 bf16x8 __attribute__((ext_vector_type(8)));
typedef float f32x4 __attribute__((ext_vector_type(4)));

#define DEV __device__ __forceinline__

static constexpr int Dm   = 1024;
static constexpr int DFFm = 4096;
static constexpr int Tm   = 2048;   // B*S tokens
static constexpr int Vm   = 32000;

// ---------------- helpers ----------------
#define GLOAD_LDS16(g, l)                                                      \
  __builtin_amdgcn_global_load_lds(                                            \
      (const __attribute__((address_space(1))) unsigned int*)(g),              \
      (__attribute__((address_space(3))) unsigned int*)(l), 16, 0, 0)

DEV float gelu_tanh(float v) {  // matches jax.nn.gelu (approximate=True)
  float u = 0.7978845608028654f * (v + 0.044715f * v * v * v);
  float e = __expf(2.0f * u);
  float t = 1.0f - 2.0f / (e + 1.0f);
  return 0.5f * v * (1.0f + t);
}

// =======================================================================
// 256^2 / 8-wave / 8-phase GEMM (logits): C = A[M][K]·B^T + bias
// Per K-tile (BK=64): 4 phases, each {ds_reads, 2 stage loads, barrier,
// lgkmcnt(0), setprio, 16 MFMA (m-quadrant x K=64), setprio, barrier}.
// Consumption ledger: B(t) fully read in phase (t,0); A-load j (rows 64j..)
// read in phases (t, 2(j&1)) .. so tile t+2's loads are staged into the
// regions of buf[t&1] right after their last reader's post-barrier:
//   (t,0): A1,A3(t+1)   [buf[(t+1)&1]; t-1's A1,A3 done after (t-1,3)]
//   (t,1): B0,B1(t+2)   [B(t) done after (t,0) post-barrier]
//   (t,2): B2,B3(t+2)
//   (t,3): A0,A2(t+2)   [A0,A2(t) done after (t,1) post-barrier]
// Gate: vmcnt(6) at phase 3 => tile t+1 fully landed (6 newer loads = t+2's),
// never drains to 0 in the main loop (T3/T4). T2 swizzle, T5 setprio.
// =======================================================================
template <bool SWZ>
__launch_bounds__(512, 2)
__global__ void gemm256_8p(const bf16* __restrict__ A, const bf16* __restrict__ B,
                           const float* __restrict__ bias, float* __restrict__ out,
                           int Kc, int Nc) {
  __shared__ bf16 lds[65536];   // 128 KiB: 2 buf x (A[256][64] | B[256][64])
  const int tid  = threadIdx.x;
  const int lane = tid & 63;
  const int wid  = tid >> 6;    // 8 waves: wr in {0,1}, wc in {0..3}
  const int wr   = wid >> 2;
  const int wc   = wid & 3;

  int bx = blockIdx.x, by = blockIdx.y;
  if constexpr (SWZ) {
    const int gx = gridDim.x, gy = gridDim.y;
    const int nwg = gx * gy;
    const int lin = by * gx + bx;
    const int q = nwg >> 3, r = nwg & 7;
    const int xcd = lin & 7, loc = lin >> 3;
    const int nid = (xcd < r ? xcd * (q + 1) : r * (q + 1) + (xcd - r) * q) + loc;
    bx = nid / gy; by = nid % gy;
  }
  const long am0 = (long)by * 256;
  const long bn0 = (long)bx * 256;
  const long K = Kc;
  const int NT = Kc >> 6;

  // staging: row = j*64 + wid*8 + (lane>>3); global chunk (lane&7)^(lane>>3)
  // lands at LDS chunk lane&7 (row-XOR swizzle; LDS dest linear per wave).
  const int sub = (lane & 7) ^ (lane >> 3);
  const int rw  = wid * 8 + (lane >> 3);
  const bf16 *aS[4], *bS[4];
#pragma unroll
  for (int j = 0; j < 4; ++j) {
    aS[j] = A + (am0 + j * 64 + rw) * K + sub * 8;
    bS[j] = B + (bn0 + j * 64 + rw) * K + sub * 8;
  }
  char* ldsc = (char*)(void*)lds;

#define STG_A(kt, j)                                                           \
  GLOAD_LDS16(aS[j] + (long)(kt) * 64,                                         \
              ldsc + ((kt) & 1) * 65536 + ((j) * 64 + wid * 8) * 128)
#define STG_B(kt, j)                                                           \
  GLOAD_LDS16(bS[j] + (long)(kt) * 64,                                         \
              ldsc + ((kt) & 1) * 65536 + 32768 + ((j) * 64 + wid * 8) * 128)

  // prologue: tile0 all 8; tile1 B0-3,A0,A2 (A1,A3 staged in (0,0))
  STG_B(0, 0); STG_B(0, 1); STG_B(0, 2); STG_B(0, 3);
  STG_A(0, 0); STG_A(0, 2); STG_A(0, 1); STG_A(0, 3);
  if (NT > 1) {
    STG_B(1, 0); STG_B(1, 1); STG_B(1, 2); STG_B(1, 3);
    STG_A(1, 0); STG_A(1, 2);
    asm volatile("s_waitcnt vmcnt(6)" ::: "memory");   // tile0 landed
  } else {
    asm volatile("s_waitcnt vmcnt(0)" ::: "memory");
  }
  __builtin_amdgcn_s_barrier();

  f32x4 acc[8][4] = {};
  const int r15 = lane & 15;
  const int kcs = lane >> 4;
  const int x7  = lane & 7;           // == r15&7 (frag row & 7)
  const int q80 = (kcs ^ x7) << 3;    // k-half 0 swizzled chunk (elems)
  const int q81 = ((kcs + 4) ^ x7) << 3;

  for (int t = 0; t < NT; ++t) {
    const bf16* LAb = lds + (t & 1) * 32768 + wr * 128 * 64;
    const bf16* LBb = lds + (t & 1) * 32768 + 16384 + wc * 64 * 64;
    bf16x8 b0[4], b1[4];

    // ---------- phase 0: m0-1; read all B frags; stage A1,A3(t+1) ----------
    {
      bf16x8 a0, a1, a2, a3;
#pragma unroll
      for (int n = 0; n < 4; ++n) {
        b0[n] = *(const bf16x8*)(LBb + (n * 16 + r15) * 64 + q80);
        b1[n] = *(const bf16x8*)(LBb + (n * 16 + r15) * 64 + q81);
      }
      a0 = *(const bf16x8*)(LAb + (0 * 16 + r15) * 64 + q80);
      a1 = *(const bf16x8*)(LAb + (0 * 16 + r15) * 64 + q81);
      a2 = *(const bf16x8*)(LAb + (1 * 16 + r15) * 64 + q80);
      a3 = *(const bf16x8*)(LAb + (1 * 16 + r15) * 64 + q81);
      if (t + 1 < NT) { STG_A(t + 1, 1); STG_A(t + 1, 3); }
      __builtin_amdgcn_s_barrier();
      asm volatile("s_waitcnt lgkmcnt(0)" ::: "memory");
      __builtin_amdgcn_s_setprio(1);
#pragma unroll
      for (int n = 0; n < 4; ++n) {
        acc[0][n] = __builtin_amdgcn_mfma_f32_16x16x32_bf16(a0, b0[n], acc[0][n], 0, 0, 0);
        acc[0][n] = __builtin_amdgcn_mfma_f32_16x16x32_bf16(a1, b1[n], acc[0][n], 0, 0, 0);
        acc[1][n] = __builtin_amdgcn_mfma_f32_16x16x32_bf16(a2, b0[n], acc[1][n], 0, 0, 0);
        acc[1][n] = __builtin_amdgcn_mfma_f32_16x16x32_bf16(a3, b1[n], acc[1][n], 0, 0, 0);
      }
      __builtin_amdgcn_s_setprio(0);
      __builtin_amdgcn_s_barrier();
    }
    // ---------- phase 1: m2-3; stage B0,B1(t+2) ----------
    {
      bf16x8 a0, a1, a2, a3;
      a0 = *(const bf16x8*)(LAb + (2 * 16 + r15) * 64 + q80);
      a1 = *(const bf16x8*)(LAb + (2 * 16 + r15) * 64 + q81);
      a2 = *(const bf16x8*)(LAb + (3 * 16 + r15) * 64 + q80);
      a3 = *(const bf16x8*)(LAb + (3 * 16 + r15) * 64 + q81);
      if (t + 2 < NT) { STG_B(t + 2, 0); STG_B(t + 2, 1); }
      __builtin_amdgcn_s_barrier();
      asm volatile("s_waitcnt lgkmcnt(0)" ::: "memory");
      __builtin_amdgcn_s_setprio(1);
#pragma unroll
      for (int n = 0; n < 4; ++n) {
        acc[2][n] = __builtin_amdgcn_mfma_f32_16x16x32_bf16(a0, b0[n], acc[2][n], 0, 0, 0);
        acc[2][n] = __builtin_amdgcn_mfma_f32_16x16x32_bf16(a1, b1[n], acc[2][n], 0, 0, 0);
        acc[3][n] = __builtin_amdgcn_mfma_f32_16x16x32_bf16(a2, b0[n], acc[3][n], 0, 0, 0);
        acc[3][n] = __builtin_amdgcn_mfma_f32_16x16x32_bf16(a3, b1[n], acc[3][n], 0, 0, 0);
      }
      __builtin_amdgcn_s_setprio(0);
      __builtin_amdgcn_s_barrier();
    }
    // ---------- phase 2: m4-5; stage B2,B3(t+2) ----------
    {
      bf16x8 a0, a1, a2, a3;
      a0 = *(const bf16x8*)(LAb + (4 * 16 + r15) * 64 + q80);
      a1 = *(const bf16x8*)(LAb + (4 * 16 + r15) * 64 + q81);
      a2 = *(const bf16x8*)(LAb + (5 * 16 + r15) * 64 + q80);
      a3 = *(const bf16x8*)(LAb + (5 * 16 + r15) * 64 + q81);
      if (t + 2 < NT) { STG_B(t + 2, 2); STG_B(t + 2, 3); }
      __builtin_amdgcn_s_barrier();
      asm volatile("s_waitcnt lgkmcnt(0)" ::: "memory");
      __builtin_amdgcn_s_setprio(1);
#pragma unroll
      for (int n = 0; n < 4; ++n) {
        acc[4][n] = __builtin_amdgcn_mfma_f32_16x16x32_bf16(a0, b0[n], acc[4][n], 0, 0, 0);
        acc[4][n] = __builtin_amdgcn_mfma_f32_16x16x32_bf16(a1, b1[n], acc[4][n], 0, 0, 0);
        acc[5][n] = __builtin_amdgcn_mfma_f32_16x16x32_bf16(a2, b0[n], acc[5][n], 0, 0, 0);
        acc[5][n] = __builtin_amdgcn_mfma_f32_16x16x32_bf16(a3, b1[n], acc[5][n], 0, 0, 0);
      }
      __builtin_amdgcn_s_setprio(0);
      __builtin_amdgcn_s_barrier();
    }
    // ---------- phase 3: m6-7; stage A0,A2(t+2); vmcnt gate ----------
    {
      bf16x8 a0, a1, a2, a3;
      a0 = *(const bf16x8*)(LAb + (6 * 16 + r15) * 64 + q80);
      a1 = *(const bf16x8*)(LAb + (6 * 16 + r15) * 64 + q81);
      a2 = *(const bf16x8*)(LAb + (7 * 16 + r15) * 64 + q80);
      a3 = *(const bf16x8*)(LAb + (7 * 16 + r15) * 64 + q81);
      if (t + 2 < NT) {
        STG_A(t + 2, 0); STG_A(t + 2, 2);
        asm volatile("s_waitcnt vmcnt(6)" ::: "memory");   // tile t+1 landed
      } else if (t + 1 < NT) {
        asm volatile("s_waitcnt vmcnt(0)" ::: "memory");   // last prefetch drain
      }
      __builtin_amdgcn_s_barrier();
      asm volatile("s_waitcnt lgkmcnt(0)" ::: "memory");
      __builtin_amdgcn_s_setprio(1);
#pragma unroll
      for (int n = 0; n < 4; ++n) {
        acc[6][n] = __builtin_amdgcn_mfma_f32_16x16x32_bf16(a0, b0[n], acc[6][n], 0, 0, 0);
        acc[6][n] = __builtin_amdgcn_mfma_f32_16x16x32_bf16(a1, b1[n], acc[6][n], 0, 0, 0);
        acc[7][n] = __builtin_amdgcn_mfma_f32_16x16x32_bf16(a2, b0[n], acc[7][n], 0, 0, 0);
        acc[7][n] = __builtin_amdgcn_mfma_f32_16x16x32_bf16(a3, b1[n], acc[7][n], 0, 0, 0);
      }
      __builtin_amdgcn_s_setprio(0);
      __builtin_amdgcn_s_barrier();
    }
  }
#undef STG_A
#undef STG_B

  const long N = Nc;
#pragma unroll
  for (int m = 0; m < 8; ++m) {
#pragma unroll
    for (int n = 0; n < 4; ++n) {
      const long col = bn0 + wc * 64 + n * 16 + r15;
      const float bv = bias[col];
#pragma unroll
      for (int r = 0; r < 4; ++r) {
        const long row = am0 + wr * 128 + m * 16 + (lane >> 4) * 4 + r;
        out[row * N + col] = acc[m][n][r] + bv;
      }
    }
  }
}

// ---------------- 128^2 GEMM: R4/R5 verified structure ----------------
enum { EPI_GELU_SPLIT = 0, EPI_RESID = 1, EPI_GELU_BF16 = 2, EPI_MOE = 3 };

struct GemmP {
  const bf16* Ah;
  const bf16* Bh;
  const float* bias;
  const float* rwp;     // routing weights [T][8]
  const int* cnt;       // per-expert token counts [8]
  const int* idx;       // per-expert token lists [8][2048]
  float* outF;
  bf16* outH;
  int K; int N;
  int lda; int ldb; int ldo;
  long aBS, bBS, outBS;        // per-ze strides
  int biasBS;
  int ebase;                   // global expert base for ze=0
  int kcShift; int kcK;        // split-K: z = (ze << kcShift) | kc
};

template <int EPI, bool GATHER, bool SWZ>
__launch_bounds__(256, 2)
__global__ void gemm_bt(GemmP p) {
  __shared__ bf16 lds[16384];          // A[128][64] | B[128][64], 32 KiB
  bf16* ldsA = lds;
  bf16* ldsB = lds + 8192;

  const int tid  = threadIdx.x;
  const int lane = tid & 63;
  const int wid  = tid >> 6;
  const int wr   = wid >> 1;
  const int wc   = wid & 1;
  const int z    = blockIdx.z;
  const int kc   = z & ((1 << p.kcShift) - 1);
  const int ze   = z >> p.kcShift;

  int bx = blockIdx.x, by = blockIdx.y;
  if constexpr (SWZ) {
    const int gx = gridDim.x, gy = gridDim.y;
    const int nwg = gx * gy;
    const int lin = by * gx + bx;
    const int q = nwg >> 3, r = nwg & 7;
    const int xcd = lin & 7, loc = lin >> 3;
    const int nid = (xcd < r ? xcd * (q + 1) : r * (q + 1) + (xcd - r) * q) + loc;
    bx = nid / gy; by = nid % gy;
  }

  const long am0 = (long)by * 128;
  const long bn0 = (long)bx * 128;

  int cntE = 0;
  const int* il = nullptr;
  if constexpr (GATHER || EPI == EPI_MOE) {
    cntE = p.cnt[p.ebase + ze];
    if (am0 >= cntE) return;  // wave-uniform early exit (before any barrier)
    il = p.idx + (long)(p.ebase + ze) * 2048;
  }

  const long lda = p.lda, ldb = p.ldb;
  const long K = p.K;
  const long kco = (long)kc * p.kcK;

  const int sub = (lane & 7) ^ (lane >> 3);
  const int rIn = wid * 8 + (lane >> 3);

  const bf16 *aS[4], *bS[4];
  {
    const bf16* Bb = p.Bh + (long)ze * p.bBS + kco + bn0 * ldb;
    const bf16* Ab = p.Ah + (long)ze * p.aBS + kco + am0 * lda;
#pragma unroll
    for (int j = 0; j < 4; ++j) {
      const int row = j * 32 + rIn;
      bS[j] = Bb + (long)row * ldb + sub * 8;
      if constexpr (GATHER) {
        const int rt = (int)am0 + row;
        const long grow = il[rt < cntE ? rt : 0];
        aS[j] = p.Ah + grow * lda + kco + sub * 8;
      } else {
        aS[j] = Ab + (long)row * lda + sub * 8;
      }
    }
  }
  char* dstA[4];
#pragma unroll
  for (int j = 0; j < 4; ++j)
    dstA[j] = (char*)(void*)lds + (j * 256 + wid * 64) * 16;

  f32x4 acc[4][4] = {};

  const int r15 = lane & 15;
  const int kcs = lane >> 4;
  const int xk  = lane & 7;

  for (long k0 = 0; k0 < K; k0 += 64) {
    __syncthreads();
#pragma unroll
    for (int j = 0; j < 4; ++j) {
      GLOAD_LDS16(aS[j] + k0, dstA[j]);
      GLOAD_LDS16(bS[j] + k0, dstA[j] + 16384);
    }
    __syncthreads();
#pragma unroll
    for (int h = 0; h < 2; ++h) {
      const int q8 = ((kcs + 4 * h) ^ xk) << 3;
      bf16x8 a[4], b[4];
#pragma unroll
      for (int m = 0; m < 4; ++m)
        a[m] = *(const bf16x8*)(ldsA + (wr * 64 + m * 16 + r15) * 64 + q8);
#pragma unroll
      for (int n = 0; n < 4; ++n)
        b[n] = *(const bf16x8*)(ldsB + (wc * 64 + n * 16 + r15) * 64 + q8);
#pragma unroll
      for (int m = 0; m < 4; ++m)
#pragma unroll
        for (int n = 0; n < 4; ++n)
          acc[m][n] = __builtin_amdgcn_mfma_f32_16x16x32_bf16(a[m], b[n], acc[m][n], 0, 0, 0);
    }
  }

  const long N = p.N;
#pragma unroll
  for (int m = 0; m < 4; ++m) {
#pragma unroll
    for (int n = 0; n < 4; ++n) {
      const long col = bn0 + wc * 64 + n * 16 + (lane & 15);
      const float bv = (kc == 0) ? p.bias[(long)ze * p.biasBS + col] : 0.0f;
#pragma unroll
      for (int r = 0; r < 4; ++r) {
        const long row = am0 + wr * 64 + m * 16 + (lane >> 4) * 4 + r;
        float v = acc[m][n][r] + bv;
        if constexpr (EPI == EPI_GELU_SPLIT) {
          float g = gelu_tanh(v);
          bf16 hh = (bf16)g;
          long o = row * (long)p.ldo + col;
          p.outH[o] = hh;
          p.outH[o + N] = (bf16)(g - (float)hh);
          p.outH[o + 2 * N] = hh;
        } else if constexpr (EPI == EPI_RESID) {
          atomicAdd(p.outF + row * N + col, v);
        } else if constexpr (EPI == EPI_GELU_BF16) {
          long o = (long)ze * p.outBS + row * N + col;
          p.outH[o] = (bf16)gelu_tanh(v);
        } else if constexpr (EPI == EPI_MOE) {
          if (row < cntE) {
            const int tok = il[row];
            const float wgt = p.rwp[(long)tok * 8 + p.ebase + ze];
            atomicAdd(p.outF + (long)tok * N + col, wgt * v);
          }
        }
      }
    }
  }
}

// ------- transpose fp32 [R][C] -> bf16 [C][R] (AUG: [C][3R] = [h|h|l]) -------
template <bool AUG>
__global__ void transpose_cvt(const float* __restrict__ in, bf16* __restrict__ out,
                              int R, int C, long inBS, long outBS) {
  __shared__ float tile[32][33];
  const float* inp = in + (long)blockIdx.z * inBS;
  const long c0 = (long)blockIdx.x * 32;
  const long r0 = (long)blockIdx.y * 32;
  const int tx = threadIdx.x;  // 32
  const int ty = threadIdx.y;  // 8
#pragma unroll
  for (int i = 0; i < 4; ++i) {
    int r = ty + i * 8;
    tile[r][tx] = inp[(r0 + r) * (long)C + c0 + tx];
  }
  __syncthreads();
  const long ob = (long)blockIdx.z * outBS;
  const long stride = AUG ? 3L * R : (long)R;
#pragma unroll
  for (int i = 0; i < 4; ++i) {
    int c = ty + i * 8;
    float v = tile[tx][c];
    bf16 h = (bf16)v;
    long o = ob + (c0 + c) * stride + r0 + tx;
    out[o] = h;
    if constexpr (AUG) {
      out[o + R] = h;
      out[o + 2 * R] = (bf16)(v - (float)h);
    }
  }
}

// ------------- embedding gather -------------
__global__ void embed_kernel(const int* __restrict__ ids, const float* __restrict__ emb,
                             float* __restrict__ x) {
  const long t = blockIdx.x;
  const int id = ids[t];
  ((float4*)(x + t * 1024))[threadIdx.x] = ((const float4*)(emb + (long)id * 1024))[threadIdx.x];
}

// ------------- LayerNorm -> augmented bf16 [h|l|h] row (stride 3072) -------------
__global__ void ln_aug_kernel(const float* __restrict__ x, const float* __restrict__ sc,
                              const float* __restrict__ bi, bf16* __restrict__ oa) {
  const long t = blockIdx.x;
  const int tid = threadIdx.x;  // 256
  const int lane = tid & 63, wid = tid >> 6;
  float4 a = ((const float4*)(x + t * 1024))[tid];
  float s = a.x + a.y + a.z + a.w;
  float q = a.x * a.x + a.y * a.y + a.z * a.z + a.w * a.w;
#pragma unroll
  for (int off = 32; off; off >>= 1) {
    s += __shfl_down(s, off);
    q += __shfl_down(q, off);
  }
  __shared__ float sr[4], qr[4];
  if (lane == 0) { sr[wid] = s; qr[wid] = q; }
  __syncthreads();
  s = sr[0] + sr[1] + sr[2] + sr[3];
  q = qr[0] + qr[1] + qr[2] + qr[3];
  const float mu = s * (1.0f / 1024.0f);
  const float var = q * (1.0f / 1024.0f) - mu * mu;
  const float rs = rsqrtf(var + 1e-5f);
#pragma unroll
  for (int j = 0; j < 4; ++j) {
    const int d = tid * 4 + j;
    const float g = (((const float*)&a)[j] - mu) * rs * sc[d] + bi[d];
    const bf16 h = (bf16)g;
    oa[t * 3072 + d] = h;
    oa[t * 3072 + 1024 + d] = (bf16)(g - (float)h);
    oa[t * 3072 + 2048 + d] = h;
  }
}

// ------------- router: logits, top-2 softmax, scatter + top2 record -------------
__global__ void router_kernel(const float* __restrict__ x, const float* __restrict__ Wr,
                              const float* __restrict__ br, float* __restrict__ rwo,
                              int* __restrict__ top2) {
  const long t = blockIdx.x;
  const int lane = threadIdx.x;  // 64
  float acc[8];
#pragma unroll
  for (int e = 0; e < 8; ++e) acc[e] = 0.0f;
  const float4* xr = (const float4*)(x + t * 1024);
#pragma unroll
  for (int j = 0; j < 4; ++j) {
    const int d4 = j * 64 + lane;
    float4 xv = xr[d4];
#pragma unroll
    for (int u = 0; u < 4; ++u) {
      const float xs = ((const float*)&xv)[u];
      const float4* wp = (const float4*)(Wr + (long)(d4 * 4 + u) * 8);
      float4 w0 = wp[0], w1 = wp[1];
      acc[0] += xs * w0.x; acc[1] += xs * w0.y; acc[2] += xs * w0.z; acc[3] += xs * w0.w;
      acc[4] += xs * w1.x; acc[5] += xs * w1.y; acc[6] += xs * w1.z; acc[7] += xs * w1.w;
    }
  }
#pragma unroll
  for (int off = 32; off; off >>= 1)
#pragma unroll
    for (int e = 0; e < 8; ++e) acc[e] += __shfl_down(acc[e], off);
  if (lane == 0) {
    float v[8];
#pragma unroll
    for (int e = 0; e < 8; ++e) v[e] = acc[e] + br[e];
    int i0 = 0; float v0 = v[0];
    for (int e = 1; e < 8; ++e) if (v[e] > v0) { v0 = v[e]; i0 = e; }
    int i1 = -1; float v1 = -3.4e38f;
    for (int e = 0; e < 8; ++e) if (e != i0 && v[e] > v1) { v1 = v[e]; i1 = e; }
    float e1 = expf(v1 - v0);
    float den = 1.0f + e1;
    float w0 = 1.0f / den, w1 = e1 / den;
    float* o = rwo + t * 8;
#pragma unroll
    for (int e = 0; e < 8; ++e) o[e] = (e == i0) ? w0 : (e == i1 ? w1 : 0.0f);
    top2[t] = i0 | (i1 << 8);
  }
}

// ------------- per-expert token list build (order-free) -------------
__global__ void build_lists(const int* __restrict__ top2, int* __restrict__ cnt,
                            int* __restrict__ idx) {
  const int t = blockIdx.x * 256 + threadIdx.x;
  const int rec = top2[t];
  const int e0 = rec & 255, e1 = (rec >> 8) & 255;
  int p0 = atomicAdd(&cnt[e0], 1);
  idx[e0 * 2048 + p0] = t;
  int p1 = atomicAdd(&cnt[e1], 1);
  idx[e1 * 2048 + p1] = t;
}

// ------------- fp32 -> bf16 flat convert -------------
__global__ void cvt_bf16_kernel(const float* __restrict__ in, bf16* __restrict__ out, long n) {
  long i = ((long)blockIdx.x * blockDim.x + threadIdx.x) * 8;
  if (i >= n) return;
  float4 a = *(const float4*)(in + i);
  float4 b = *(const float4*)(in + i + 4);
  bf16x8 o;
  o[0] = (bf16)a.x; o[1] = (bf16)a.y; o[2] = (bf16)a.z; o[3] = (bf16)a.w;
  o[4] = (bf16)b.x; o[5] = (bf16)b.y; o[6] = (bf16)b.z; o[7] = (bf16)b.w;
  *(bf16x8*)(out + i) = o;
}

// ---------------- host launch ----------------
extern "C" void kernel_launch(void* const* d_in, const int* in_sizes, int n_in,
                              void* d_out, int out_size, void* d_ws, size_t ws_size,
                              hipStream_t stream) {
  (void)in_sizes; (void)n_in; (void)out_size; (void)ws_size;
  const int*   ids  = (const int*)d_in[0];
  const float* emb  = (const float*)d_in[1];
  const float* tlns = (const float*)d_in[2];
  const float* tlnb = (const float*)d_in[3];
  const float* tw1  = (const float*)d_in[4];
  const float* tb1  = (const float*)d_in[5];
  const float* tw2  = (const float*)d_in[6];
  const float* tb2  = (const float*)d_in[7];
  const float* Wr   = (const float*)d_in[8];
  const float* br   = (const float*)d_in[9];
  const float* ew1  = (const float*)d_in[10];
  const float* eb1  = (const float*)d_in[11];
  const float* ew2  = (const float*)d_in[12];
  const float* eb2  = (const float*)d_in[13];
  const float* Wl   = (const float*)d_in[14];
  const float* bl   = (const float*)d_in[15];

  float* logits = (float*)d_out;
  float* rwout  = (float*)d_out + (long)Tm * Vm;

  size_t off = 0;
  auto take = [&](size_t bytes) {
    void* pp = (char*)d_ws + off;
    off += (bytes + 255) & ~(size_t)255;
    return pp;
  };
  float* X    = (float*)take((size_t)Tm * Dm * 4);
  bf16*  XB   = (bf16*) take((size_t)Tm * Dm * 2);
  float* Y    = (float*)take((size_t)Tm * Dm * 4);
  bf16*  YB   = (bf16*) take((size_t)Tm * Dm * 2);
  int*   top2 = (int*)  take((size_t)Tm * 4);
  int*   cnt  = (int*)  take(8 * 4);
  int*   idxl = (int*)  take((size_t)8 * Tm * 4);
  char*  S    = (char*) take(134217728);   // 128 MiB phase-shared scratch

  // temporal phase
  bf16* A1  = (bf16*)S;                              // [2048][3072]  12.6 MB
  bf16* W1A = (bf16*)(S + 12582912);                 // [4096][3072]  25.2 MB
  bf16* W2A = (bf16*)(S + 12582912 + 25165824);      // [1024][12288] 25.2 MB
  bf16* HTA = (bf16*)(S + 12582912 + 2 * 25165824);  // [2048][12288] 50.3 MB
  // expert phase
  bf16* EW1T = (bf16*)S;                             // 4x[4096][1024] 33.6 MB
  bf16* HE   = (bf16*)(S + 33554432);                // 4x[2048][4096] 67.1 MB
  bf16* EW2T = (bf16*)(S + 100663296);               // 4x[1024][4096] 33.6 MB
  // logits phase
  bf16* WLT  = (bf16*)S;                             // [32000][1024]  65.5 MB

  embed_kernel<<<dim3(Tm), dim3(256), 0, stream>>>(ids, emb, X);

  // ---- temporal residual MLP blocks: augmented-K plain GEMMs (R5) ----
  for (int l = 0; l < 2; ++l) {
    transpose_cvt<true><<<dim3(DFFm / 32, Dm / 32, 1), dim3(32, 8), 0, stream>>>(
        tw1 + (long)l * Dm * DFFm, W1A, Dm, DFFm, 0, 0);
    transpose_cvt<true><<<dim3(Dm / 32, DFFm / 32, 1), dim3(32, 8), 0, stream>>>(
        tw2 + (long)l * DFFm * Dm, W2A, DFFm, Dm, 0, 0);
    ln_aug_kernel<<<dim3(Tm), dim3(256), 0, stream>>>(X, tlns + l * Dm, tlnb + l * Dm, A1);

    GemmP p1{};
    p1.Ah = A1; p1.Bh = W1A;
    p1.bias = tb1 + (long)l * DFFm;
    p1.outH = HTA;
    p1.K = 3072; p1.N = DFFm; p1.lda = 3072; p1.ldb = 3072; p1.ldo = 3 * DFFm;
    gemm_bt<EPI_GELU_SPLIT, false, true>
        <<<dim3(DFFm / 128, Tm / 128, 1), dim3(256), 0, stream>>>(p1);

    // split-K z=8 (kcShift=3, chunks of 1536): 1024 blocks, 4/CU
    GemmP p2{};
    p2.Ah = HTA; p2.Bh = W2A;
    p2.bias = tb2 + (long)l * Dm;
    p2.outF = X;                         // X pre-holds residual; chunks atomicAdd
    p2.K = 1536; p2.N = Dm; p2.lda = 12288; p2.ldb = 12288;
    p2.kcShift = 3; p2.kcK = 1536;
    gemm_bt<EPI_RESID, false, true>
        <<<dim3(Dm / 128, Tm / 128, 8), dim3(256), 0, stream>>>(p2);
  }

  // ---- router (fp32) + token lists ----
  router_kernel<<<dim3(Tm), dim3(64), 0, stream>>>(X, Wr, br, rwout, top2);
  hipMemsetAsync(cnt, 0, 8 * 4, stream);
  build_lists<<<dim3(Tm / 256), dim3(256), 0, stream>>>(top2, cnt, idxl);
  cvt_bf16_kernel<<<dim3(Tm * Dm / (256 * 8)), dim3(256), 0, stream>>>(X, XB, (long)Tm * Dm);
  hipMemsetAsync(Y, 0, (size_t)Tm * Dm * 4, stream);

  // ---- sparse top-2 expert stack, 2 quads of 4 experts (bf16, 128^2) ----
  for (int q = 0; q < 2; ++q) {
    transpose_cvt<false><<<dim3(DFFm / 32, Dm / 32, 4), dim3(32, 8), 0, stream>>>(
        ew1 + (long)q * 4 * Dm * DFFm, EW1T, Dm, DFFm, (long)Dm * DFFm, (long)DFFm * Dm);
    transpose_cvt<false><<<dim3(Dm / 32, DFFm / 32, 4), dim3(32, 8), 0, stream>>>(
        ew2 + (long)q * 4 * DFFm * Dm, EW2T, DFFm, Dm, (long)DFFm * Dm, (long)Dm * DFFm);

    GemmP pe1{};
    pe1.Ah = XB; pe1.Bh = EW1T;
    pe1.bias = eb1 + (long)q * 4 * DFFm; pe1.biasBS = DFFm;
    pe1.outH = HE; pe1.outBS = (long)Tm * DFFm;
    pe1.aBS = 0; pe1.bBS = (long)DFFm * Dm;
    pe1.cnt = cnt; pe1.idx = idxl; pe1.ebase = q * 4;
    pe1.K = Dm; pe1.N = DFFm; pe1.lda = Dm; pe1.ldb = Dm;
    gemm_bt<EPI_GELU_BF16, true, true>
        <<<dim3(DFFm / 128, Tm / 128, 4), dim3(256), 0, stream>>>(pe1);

    // split-K x4 per expert: z = (e<<2)|kc, chunks of 1024
    GemmP pe2{};
    pe2.Ah = HE; pe2.aBS = (long)Tm * DFFm;
    pe2.Bh = EW2T; pe2.bBS = (long)Dm * DFFm;
    pe2.bias = eb2 + (long)q * 4 * Dm; pe2.biasBS = Dm;
    pe2.rwp = rwout; pe2.cnt = cnt; pe2.idx = idxl; pe2.ebase = q * 4;
    pe2.outF = Y;
    pe2.K = 1024; pe2.N = Dm; pe2.lda = DFFm; pe2.ldb = DFFm;
    pe2.kcShift = 2; pe2.kcK = 1024;
    gemm_bt<EPI_MOE, false, true>
        <<<dim3(Dm / 128, Tm / 128, 16), dim3(256), 0, stream>>>(pe2);
  }

  // ---- final logits GEMM: 256^2 8-phase counted-vmcnt pipeline ----
  cvt_bf16_kernel<<<dim3(Tm * Dm / (256 * 8)), dim3(256), 0, stream>>>(Y, YB, (long)Tm * Dm);
  transpose_cvt<false><<<dim3(Vm / 32, Dm / 32, 1), dim3(32, 8), 0, stream>>>(
      Wl, WLT, Dm, Vm, 0, 0);
  gemm256_8p<true><<<dim3(Vm / 256, Tm / 256, 1), dim3(512), 0, stream>>>(
      YB, WLT, bl, logits, Dm, Vm);
}

// Round 8
// 978.026 us; speedup vs baseline: 1.1429x; 1.0017x over previous
//
#include <hip/hip_runtime.h>
#include <stdint.h>

typedef __bf16 bf16;
typedef __bf16 bf16x8 __attribute__((ext_vector_type(8)));
typedef __bf16 bf16x4 __attribute__((ext_vector_type(4)));
typedef float f32x4 __attribute__((ext_vector_type(4)));

#define DEV __device__ __forceinline__

static constexpr int Dm   = 1024;
static constexpr int DFFm = 4096;
static constexpr int Tm   = 2048;   // B*S tokens
static constexpr int Vm   = 32000;

// ---------------- helpers ----------------
#define GLOAD_LDS16(g, l)                                                      \
  __builtin_amdgcn_global_load_lds(                                            \
      (const __attribute__((address_space(1))) unsigned int*)(g),              \
      (__attribute__((address_space(3))) unsigned int*)(l), 16, 0, 0)

DEV float gelu_tanh(float v) {  // matches jax.nn.gelu (approximate=True)
  float u = 0.7978845608028654f * (v + 0.044715f * v * v * v);
  float e = __expf(2.0f * u);
  float t = 1.0f - 2.0f / (e + 1.0f);
  return 0.5f * v * (1.0f + t);
}

// =======================================================================
// 256^2 / 8-wave / 8-phase GEMM (logits) — unchanged from R7 (equal-best).
// =======================================================================
template <bool SWZ>
__launch_bounds__(512, 2)
__global__ void gemm256_8p(const bf16* __restrict__ A, const bf16* __restrict__ B,
                           const float* __restrict__ bias, float* __restrict__ out,
                           int Kc, int Nc) {
  __shared__ bf16 lds[65536];   // 128 KiB: 2 buf x (A[256][64] | B[256][64])
  const int tid  = threadIdx.x;
  const int lane = tid & 63;
  const int wid  = tid >> 6;
  const int wr   = wid >> 2;
  const int wc   = wid & 3;

  int bx = blockIdx.x, by = blockIdx.y;
  if constexpr (SWZ) {
    const int gx = gridDim.x, gy = gridDim.y;
    const int nwg = gx * gy;
    const int lin = by * gx + bx;
    const int q = nwg >> 3, r = nwg & 7;
    const int xcd = lin & 7, loc = lin >> 3;
    const int nid = (xcd < r ? xcd * (q + 1) : r * (q + 1) + (xcd - r) * q) + loc;
    bx = nid / gy; by = nid % gy;
  }
  const long am0 = (long)by * 256;
  const long bn0 = (long)bx * 256;
  const long K = Kc;
  const int NT = Kc >> 6;

  const int sub = (lane & 7) ^ (lane >> 3);
  const int rw  = wid * 8 + (lane >> 3);
  const bf16 *aS[4], *bS[4];
#pragma unroll
  for (int j = 0; j < 4; ++j) {
    aS[j] = A + (am0 + j * 64 + rw) * K + sub * 8;
    bS[j] = B + (bn0 + j * 64 + rw) * K + sub * 8;
  }
  char* ldsc = (char*)(void*)lds;

#define STG_A(kt, j)                                                           \
  GLOAD_LDS16(aS[j] + (long)(kt) * 64,                                         \
              ldsc + ((kt) & 1) * 65536 + ((j) * 64 + wid * 8) * 128)
#define STG_B(kt, j)                                                           \
  GLOAD_LDS16(bS[j] + (long)(kt) * 64,                                         \
              ldsc + ((kt) & 1) * 65536 + 32768 + ((j) * 64 + wid * 8) * 128)

  STG_B(0, 0); STG_B(0, 1); STG_B(0, 2); STG_B(0, 3);
  STG_A(0, 0); STG_A(0, 2); STG_A(0, 1); STG_A(0, 3);
  if (NT > 1) {
    STG_B(1, 0); STG_B(1, 1); STG_B(1, 2); STG_B(1, 3);
    STG_A(1, 0); STG_A(1, 2);
    asm volatile("s_waitcnt vmcnt(6)" ::: "memory");
  } else {
    asm volatile("s_waitcnt vmcnt(0)" ::: "memory");
  }
  __builtin_amdgcn_s_barrier();

  f32x4 acc[8][4] = {};
  const int r15 = lane & 15;
  const int kcs = lane >> 4;
  const int x7  = lane & 7;
  const int q80 = (kcs ^ x7) << 3;
  const int q81 = ((kcs + 4) ^ x7) << 3;

  for (int t = 0; t < NT; ++t) {
    const bf16* LAb = lds + (t & 1) * 32768 + wr * 128 * 64;
    const bf16* LBb = lds + (t & 1) * 32768 + 16384 + wc * 64 * 64;
    bf16x8 b0[4], b1[4];

    {
      bf16x8 a0, a1, a2, a3;
#pragma unroll
      for (int n = 0; n < 4; ++n) {
        b0[n] = *(const bf16x8*)(LBb + (n * 16 + r15) * 64 + q80);
        b1[n] = *(const bf16x8*)(LBb + (n * 16 + r15) * 64 + q81);
      }
      a0 = *(const bf16x8*)(LAb + (0 * 16 + r15) * 64 + q80);
      a1 = *(const bf16x8*)(LAb + (0 * 16 + r15) * 64 + q81);
      a2 = *(const bf16x8*)(LAb + (1 * 16 + r15) * 64 + q80);
      a3 = *(const bf16x8*)(LAb + (1 * 16 + r15) * 64 + q81);
      if (t + 1 < NT) { STG_A(t + 1, 1); STG_A(t + 1, 3); }
      __builtin_amdgcn_s_barrier();
      asm volatile("s_waitcnt lgkmcnt(0)" ::: "memory");
      __builtin_amdgcn_s_setprio(1);
#pragma unroll
      for (int n = 0; n < 4; ++n) {
        acc[0][n] = __builtin_amdgcn_mfma_f32_16x16x32_bf16(a0, b0[n], acc[0][n], 0, 0, 0);
        acc[0][n] = __builtin_amdgcn_mfma_f32_16x16x32_bf16(a1, b1[n], acc[0][n], 0, 0, 0);
        acc[1][n] = __builtin_amdgcn_mfma_f32_16x16x32_bf16(a2, b0[n], acc[1][n], 0, 0, 0);
        acc[1][n] = __builtin_amdgcn_mfma_f32_16x16x32_bf16(a3, b1[n], acc[1][n], 0, 0, 0);
      }
      __builtin_amdgcn_s_setprio(0);
      __builtin_amdgcn_s_barrier();
    }
    {
      bf16x8 a0, a1, a2, a3;
      a0 = *(const bf16x8*)(LAb + (2 * 16 + r15) * 64 + q80);
      a1 = *(const bf16x8*)(LAb + (2 * 16 + r15) * 64 + q81);
      a2 = *(const bf16x8*)(LAb + (3 * 16 + r15) * 64 + q80);
      a3 = *(const bf16x8*)(LAb + (3 * 16 + r15) * 64 + q81);
      if (t + 2 < NT) { STG_B(t + 2, 0); STG_B(t + 2, 1); }
      __builtin_amdgcn_s_barrier();
      asm volatile("s_waitcnt lgkmcnt(0)" ::: "memory");
      __builtin_amdgcn_s_setprio(1);
#pragma unroll
      for (int n = 0; n < 4; ++n) {
        acc[2][n] = __builtin_amdgcn_mfma_f32_16x16x32_bf16(a0, b0[n], acc[2][n], 0, 0, 0);
        acc[2][n] = __builtin_amdgcn_mfma_f32_16x16x32_bf16(a1, b1[n], acc[2][n], 0, 0, 0);
        acc[3][n] = __builtin_amdgcn_mfma_f32_16x16x32_bf16(a2, b0[n], acc[3][n], 0, 0, 0);
        acc[3][n] = __builtin_amdgcn_mfma_f32_16x16x32_bf16(a3, b1[n], acc[3][n], 0, 0, 0);
      }
      __builtin_amdgcn_s_setprio(0);
      __builtin_amdgcn_s_barrier();
    }
    {
      bf16x8 a0, a1, a2, a3;
      a0 = *(const bf16x8*)(LAb + (4 * 16 + r15) * 64 + q80);
      a1 = *(const bf16x8*)(LAb + (4 * 16 + r15) * 64 + q81);
      a2 = *(const bf16x8*)(LAb + (5 * 16 + r15) * 64 + q80);
      a3 = *(const bf16x8*)(LAb + (5 * 16 + r15) * 64 + q81);
      if (t + 2 < NT) { STG_B(t + 2, 2); STG_B(t + 2, 3); }
      __builtin_amdgcn_s_barrier();
      asm volatile("s_waitcnt lgkmcnt(0)" ::: "memory");
      __builtin_amdgcn_s_setprio(1);
#pragma unroll
      for (int n = 0; n < 4; ++n) {
        acc[4][n] = __builtin_amdgcn_mfma_f32_16x16x32_bf16(a0, b0[n], acc[4][n], 0, 0, 0);
        acc[4][n] = __builtin_amdgcn_mfma_f32_16x16x32_bf16(a1, b1[n], acc[4][n], 0, 0, 0);
        acc[5][n] = __builtin_amdgcn_mfma_f32_16x16x32_bf16(a2, b0[n], acc[5][n], 0, 0, 0);
        acc[5][n] = __builtin_amdgcn_mfma_f32_16x16x32_bf16(a3, b1[n], acc[5][n], 0, 0, 0);
      }
      __builtin_amdgcn_s_setprio(0);
      __builtin_amdgcn_s_barrier();
    }
    {
      bf16x8 a0, a1, a2, a3;
      a0 = *(const bf16x8*)(LAb + (6 * 16 + r15) * 64 + q80);
      a1 = *(const bf16x8*)(LAb + (6 * 16 + r15) * 64 + q81);
      a2 = *(const bf16x8*)(LAb + (7 * 16 + r15) * 64 + q80);
      a3 = *(const bf16x8*)(LAb + (7 * 16 + r15) * 64 + q81);
      if (t + 2 < NT) {
        STG_A(t + 2, 0); STG_A(t + 2, 2);
        asm volatile("s_waitcnt vmcnt(6)" ::: "memory");
      } else if (t + 1 < NT) {
        asm volatile("s_waitcnt vmcnt(0)" ::: "memory");
      }
      __builtin_amdgcn_s_barrier();
      asm volatile("s_waitcnt lgkmcnt(0)" ::: "memory");
      __builtin_amdgcn_s_setprio(1);
#pragma unroll
      for (int n = 0; n < 4; ++n) {
        acc[6][n] = __builtin_amdgcn_mfma_f32_16x16x32_bf16(a0, b0[n], acc[6][n], 0, 0, 0);
        acc[6][n] = __builtin_amdgcn_mfma_f32_16x16x32_bf16(a1, b1[n], acc[6][n], 0, 0, 0);
        acc[7][n] = __builtin_amdgcn_mfma_f32_16x16x32_bf16(a2, b0[n], acc[7][n], 0, 0, 0);
        acc[7][n] = __builtin_amdgcn_mfma_f32_16x16x32_bf16(a3, b1[n], acc[7][n], 0, 0, 0);
      }
      __builtin_amdgcn_s_setprio(0);
      __builtin_amdgcn_s_barrier();
    }
  }
#undef STG_A
#undef STG_B

  const long N = Nc;
#pragma unroll
  for (int m = 0; m < 8; ++m) {
#pragma unroll
    for (int n = 0; n < 4; ++n) {
      const long col = bn0 + wc * 64 + n * 16 + r15;
      const float bv = bias[col];
#pragma unroll
      for (int r = 0; r < 4; ++r) {
        const long row = am0 + wr * 128 + m * 16 + (lane >> 4) * 4 + r;
        out[row * N + col] = acc[m][n][r] + bv;
      }
    }
  }
}

// ---------------- 128^2 GEMM with augmented-K wrap remap ----------------
// Virtual k in [0,K_total); phys k: ka = (kv >= aT) ? kv - aS2 : kv (same for B).
// Zero-init (aT=0,aS2=0) => identity. Boundaries are multiples of 64 => a
// 64-wide K-tile never straddles a remap boundary.
enum { EPI_GELU_SPLIT = 0, EPI_RESID = 1, EPI_GELU_BF16 = 2, EPI_MOE = 3 };

struct GemmP {
  const bf16* Ah;
  const bf16* Bh;
  const float* bias;
  const float* rwp;     // routing weights [T][8]
  const int* cnt;       // per-expert token counts [8]
  const int* idx;       // per-expert token lists [8][2048]
  float* outF;
  bf16* outH;
  int K; int N;
  int lda; int ldb; int ldo;
  long aBS, bBS, outBS;        // per-ze strides
  int biasBS;
  int ebase;                   // global expert base for ze=0
  int kcShift; int kcK;        // split-K: z = (ze << kcShift) | kc
  int aT, aS2, bT, bS2;        // k-wrap remap (0 => identity)
};

template <int EPI, bool GATHER, bool SWZ>
__launch_bounds__(256, 2)
__global__ void gemm_bt(GemmP p) {
  __shared__ bf16 lds[16384];          // A[128][64] | B[128][64], 32 KiB
  bf16* ldsA = lds;
  bf16* ldsB = lds + 8192;

  const int tid  = threadIdx.x;
  const int lane = tid & 63;
  const int wid  = tid >> 6;
  const int wr   = wid >> 1;
  const int wc   = wid & 1;
  const int z    = blockIdx.z;
  const int kc   = z & ((1 << p.kcShift) - 1);
  const int ze   = z >> p.kcShift;

  int bx = blockIdx.x, by = blockIdx.y;
  if constexpr (SWZ) {
    const int gx = gridDim.x, gy = gridDim.y;
    const int nwg = gx * gy;
    const int lin = by * gx + bx;
    const int q = nwg >> 3, r = nwg & 7;
    const int xcd = lin & 7, loc = lin >> 3;
    const int nid = (xcd < r ? xcd * (q + 1) : r * (q + 1) + (xcd - r) * q) + loc;
    bx = nid / gy; by = nid % gy;
  }

  const long am0 = (long)by * 128;
  const long bn0 = (long)bx * 128;

  int cntE = 0;
  const int* il = nullptr;
  if constexpr (GATHER || EPI == EPI_MOE) {
    cntE = p.cnt[p.ebase + ze];
    if (am0 >= cntE) return;  // wave-uniform early exit (before any barrier)
    il = p.idx + (long)(p.ebase + ze) * 2048;
  }

  const long lda = p.lda, ldb = p.ldb;
  const long K = p.K;
  const long kco = (long)kc * p.kcK;

  const int sub = (lane & 7) ^ (lane >> 3);
  const int rIn = wid * 8 + (lane >> 3);

  const bf16 *aS[4], *bS[4];
  {
    const bf16* Bb = p.Bh + (long)ze * p.bBS + bn0 * ldb;
    const bf16* Ab = p.Ah + (long)ze * p.aBS + am0 * lda;
#pragma unroll
    for (int j = 0; j < 4; ++j) {
      const int row = j * 32 + rIn;
      bS[j] = Bb + (long)row * ldb + sub * 8;
      if constexpr (GATHER) {
        const int rt = (int)am0 + row;
        const long grow = il[rt < cntE ? rt : 0];
        aS[j] = p.Ah + grow * lda + sub * 8;
      } else {
        aS[j] = Ab + (long)row * lda + sub * 8;
      }
    }
  }
  char* dstA[4];
#pragma unroll
  for (int j = 0; j < 4; ++j)
    dstA[j] = (char*)(void*)lds + (j * 256 + wid * 64) * 16;

  f32x4 acc[4][4] = {};

  const int r15 = lane & 15;
  const int kcs = lane >> 4;
  const int xk  = lane & 7;

  for (long k0 = 0; k0 < K; k0 += 64) {
    const long kv = kco + k0;
    const long ka = (kv >= p.aT) ? kv - p.aS2 : kv;
    const long kb = (kv >= p.bT) ? kv - p.bS2 : kv;
    __syncthreads();
#pragma unroll
    for (int j = 0; j < 4; ++j) {
      GLOAD_LDS16(aS[j] + ka, dstA[j]);
      GLOAD_LDS16(bS[j] + kb, dstA[j] + 16384);
    }
    __syncthreads();
#pragma unroll
    for (int h = 0; h < 2; ++h) {
      const int q8 = ((kcs + 4 * h) ^ xk) << 3;
      bf16x8 a[4], b[4];
#pragma unroll
      for (int m = 0; m < 4; ++m)
        a[m] = *(const bf16x8*)(ldsA + (wr * 64 + m * 16 + r15) * 64 + q8);
#pragma unroll
      for (int n = 0; n < 4; ++n)
        b[n] = *(const bf16x8*)(ldsB + (wc * 64 + n * 16 + r15) * 64 + q8);
#pragma unroll
      for (int m = 0; m < 4; ++m)
#pragma unroll
        for (int n = 0; n < 4; ++n)
          acc[m][n] = __builtin_amdgcn_mfma_f32_16x16x32_bf16(a[m], b[n], acc[m][n], 0, 0, 0);
    }
  }

  const long N = p.N;
#pragma unroll
  for (int m = 0; m < 4; ++m) {
#pragma unroll
    for (int n = 0; n < 4; ++n) {
      const long col = bn0 + wc * 64 + n * 16 + (lane & 15);
      const float bv = (kc == 0) ? p.bias[(long)ze * p.biasBS + col] : 0.0f;
#pragma unroll
      for (int r = 0; r < 4; ++r) {
        const long row = am0 + wr * 64 + m * 16 + (lane >> 4) * 4 + r;
        float v = acc[m][n][r] + bv;
        if constexpr (EPI == EPI_GELU_SPLIT) {
          // write [h|l] row (phys stride ldo = 2N)
          float g = gelu_tanh(v);
          bf16 hh = (bf16)g;
          long o = row * (long)p.ldo + col;
          p.outH[o] = hh;
          p.outH[o + N] = (bf16)(g - (float)hh);
        } else if constexpr (EPI == EPI_RESID) {
          atomicAdd(p.outF + row * N + col, v);
        } else if constexpr (EPI == EPI_GELU_BF16) {
          long o = (long)ze * p.outBS + row * N + col;
          p.outH[o] = (bf16)gelu_tanh(v);
        } else if constexpr (EPI == EPI_MOE) {
          if (row < cntE) {
            const int tok = il[row];
            const float wgt = p.rwp[(long)tok * 8 + p.ebase + ze];
            atomicAdd(p.outF + (long)tok * N + col, wgt * v);
          }
        }
      }
    }
  }
}

// ------- fast transpose: fp32 [R][C] -> bf16 [C][R] (AUG: [C][2R]=[h|l]) -----
// 64x64 tile, 256 threads (16x16), float4 loads, bf16x4 stores, [64][65] LDS.
template <bool AUG>
__global__ void transpose_cvt(const float* __restrict__ in, bf16* __restrict__ out,
                              int R, int C, long inBS, long outBS) {
  __shared__ float tile[64][65];
  const float* inp = in + (long)blockIdx.z * inBS;
  const long c0 = (long)blockIdx.x * 64;
  const long r0 = (long)blockIdx.y * 64;
  const int tx = threadIdx.x;   // 16
  const int ty = threadIdx.y;   // 16
#pragma unroll
  for (int i = 0; i < 4; ++i) {
    const int r = ty + i * 16;
    const float4 v = *(const float4*)(inp + (r0 + r) * (long)C + c0 + tx * 4);
    tile[r][tx * 4 + 0] = v.x;
    tile[r][tx * 4 + 1] = v.y;
    tile[r][tx * 4 + 2] = v.z;
    tile[r][tx * 4 + 3] = v.w;
  }
  __syncthreads();
  const long ob = (long)blockIdx.z * outBS;
  const long stride = AUG ? 2L * R : (long)R;
#pragma unroll
  for (int j = 0; j < 4; ++j) {
    const int c = j * 16 + ty;
    bf16x4 h, l;
#pragma unroll
    for (int u = 0; u < 4; ++u) {
      float v = tile[tx * 4 + u][c];
      bf16 hh = (bf16)v;
      h[u] = hh;
      if constexpr (AUG) l[u] = (bf16)(v - (float)hh);
    }
    const long o = ob + (c0 + c) * stride + r0 + tx * 4;
    *(bf16x4*)(out + o) = h;
    if constexpr (AUG) *(bf16x4*)(out + o + R) = l;
  }
}

// ------------- embedding gather -------------
__global__ void embed_kernel(const int* __restrict__ ids, const float* __restrict__ emb,
                             float* __restrict__ x) {
  const long t = blockIdx.x;
  const int id = ids[t];
  ((float4*)(x + t * 1024))[threadIdx.x] = ((const float4*)(emb + (long)id * 1024))[threadIdx.x];
}

// ------------- LayerNorm -> bf16 [h|l] row (stride 2048) -------------
__global__ void ln_aug2_kernel(const float* __restrict__ x, const float* __restrict__ sc,
                               const float* __restrict__ bi, bf16* __restrict__ oa) {
  const long t = blockIdx.x;
  const int tid = threadIdx.x;  // 256
  const int lane = tid & 63, wid = tid >> 6;
  float4 a = ((const float4*)(x + t * 1024))[tid];
  float s = a.x + a.y + a.z + a.w;
  float q = a.x * a.x + a.y * a.y + a.z * a.z + a.w * a.w;
#pragma unroll
  for (int off = 32; off; off >>= 1) {
    s += __shfl_down(s, off);
    q += __shfl_down(q, off);
  }
  __shared__ float sr[4], qr[4];
  if (lane == 0) { sr[wid] = s; qr[wid] = q; }
  __syncthreads();
  s = sr[0] + sr[1] + sr[2] + sr[3];
  q = qr[0] + qr[1] + qr[2] + qr[3];
  const float mu = s * (1.0f / 1024.0f);
  const float var = q * (1.0f / 1024.0f) - mu * mu;
  const float rs = rsqrtf(var + 1e-5f);
#pragma unroll
  for (int j = 0; j < 4; ++j) {
    const int d = tid * 4 + j;
    const float g = (((const float*)&a)[j] - mu) * rs * sc[d] + bi[d];
    const bf16 h = (bf16)g;
    oa[t * 2048 + d] = h;
    oa[t * 2048 + 1024 + d] = (bf16)(g - (float)h);
  }
}

// ---- router fused: logits, top-2 softmax scatter, expert lists, X->bf16 ----
__global__ void router_kernel(const float* __restrict__ x, const float* __restrict__ Wr,
                              const float* __restrict__ br, float* __restrict__ rwo,
                              bf16* __restrict__ xb, int* __restrict__ cnt,
                              int* __restrict__ idx) {
  const long t = blockIdx.x;
  const int lane = threadIdx.x;  // 64
  float acc[8];
#pragma unroll
  for (int e = 0; e < 8; ++e) acc[e] = 0.0f;
  const float4* xr = (const float4*)(x + t * 1024);
#pragma unroll
  for (int j = 0; j < 4; ++j) {
    const int d4 = j * 64 + lane;
    float4 xv = xr[d4];
    bf16x4 xh;
    xh[0] = (bf16)xv.x; xh[1] = (bf16)xv.y; xh[2] = (bf16)xv.z; xh[3] = (bf16)xv.w;
    *(bf16x4*)(xb + t * 1024 + (long)d4 * 4) = xh;
#pragma unroll
    for (int u = 0; u < 4; ++u) {
      const float xs = ((const float*)&xv)[u];
      const float4* wp = (const float4*)(Wr + (long)(d4 * 4 + u) * 8);
      float4 w0 = wp[0], w1 = wp[1];
      acc[0] += xs * w0.x; acc[1] += xs * w0.y; acc[2] += xs * w0.z; acc[3] += xs * w0.w;
      acc[4] += xs * w1.x; acc[5] += xs * w1.y; acc[6] += xs * w1.z; acc[7] += xs * w1.w;
    }
  }
#pragma unroll
  for (int off = 32; off; off >>= 1)
#pragma unroll
    for (int e = 0; e < 8; ++e) acc[e] += __shfl_down(acc[e], off);
  if (lane == 0) {
    float v[8];
#pragma unroll
    for (int e = 0; e < 8; ++e) v[e] = acc[e] + br[e];
    int i0 = 0; float v0 = v[0];
    for (int e = 1; e < 8; ++e) if (v[e] > v0) { v0 = v[e]; i0 = e; }
    int i1 = -1; float v1 = -3.4e38f;
    for (int e = 0; e < 8; ++e) if (e != i0 && v[e] > v1) { v1 = v[e]; i1 = e; }
    float e1 = expf(v1 - v0);
    float den = 1.0f + e1;
    float w0 = 1.0f / den, w1 = e1 / den;
    float* o = rwo + t * 8;
#pragma unroll
    for (int e = 0; e < 8; ++e) o[e] = (e == i0) ? w0 : (e == i1 ? w1 : 0.0f);
    int p0 = atomicAdd(&cnt[i0], 1);
    idx[i0 * 2048 + p0] = (int)t;
    int p1 = atomicAdd(&cnt[i1], 1);
    idx[i1 * 2048 + p1] = (int)t;
  }
}

// ------------- fp32 -> bf16 flat convert (YB) -------------
__global__ void cvt_bf16_kernel(const float* __restrict__ in, bf16* __restrict__ out, long n) {
  long i = ((long)blockIdx.x * blockDim.x + threadIdx.x) * 8;
  if (i >= n) return;
  float4 a = *(const float4*)(in + i);
  float4 b = *(const float4*)(in + i + 4);
  bf16x8 o;
  o[0] = (bf16)a.x; o[1] = (bf16)a.y; o[2] = (bf16)a.z; o[3] = (bf16)a.w;
  o[4] = (bf16)b.x; o[5] = (bf16)b.y; o[6] = (bf16)b.z; o[7] = (bf16)b.w;
  *(bf16x8*)(out + i) = o;
}

// ---------------- host launch ----------------
extern "C" void kernel_launch(void* const* d_in, const int* in_sizes, int n_in,
                              void* d_out, int out_size, void* d_ws, size_t ws_size,
                              hipStream_t stream) {
  (void)in_sizes; (void)n_in; (void)out_size; (void)ws_size;
  const int*   ids  = (const int*)d_in[0];
  const float* emb  = (const float*)d_in[1];
  const float* tlns = (const float*)d_in[2];
  const float* tlnb = (const float*)d_in[3];
  const float* tw1  = (const float*)d_in[4];
  const float* tb1  = (const float*)d_in[5];
  const float* tw2  = (const float*)d_in[6];
  const float* tb2  = (const float*)d_in[7];
  const float* Wr   = (const float*)d_in[8];
  const float* br   = (const float*)d_in[9];
  const float* ew1  = (const float*)d_in[10];
  const float* eb1  = (const float*)d_in[11];
  const float* ew2  = (const float*)d_in[12];
  const float* eb2  = (const float*)d_in[13];
  const float* Wl   = (const float*)d_in[14];
  const float* bl   = (const float*)d_in[15];

  float* logits = (float*)d_out;
  float* rwout  = (float*)d_out + (long)Tm * Vm;

  size_t off = 0;
  auto take = [&](size_t bytes) {
    void* pp = (char*)d_ws + off;
    off += (bytes + 255) & ~(size_t)255;
    return pp;
  };
  float* X    = (float*)take((size_t)Tm * Dm * 4);
  bf16*  XB   = (bf16*) take((size_t)Tm * Dm * 2);
  float* Y    = (float*)take((size_t)Tm * Dm * 4);
  bf16*  YB   = (bf16*) take((size_t)Tm * Dm * 2);
  int*   cnt  = (int*)  take(8 * 4);
  int*   idxl = (int*)  take((size_t)8 * Tm * 4);
  char*  S    = (char*) take(134217728);   // 128 MiB phase-shared scratch

  // temporal phase ([h|l] compressed augmented layout + k-wrap remap)
  bf16* A1  = (bf16*)S;                    // [2048][2048]   8.4 MB
  bf16* W1A = (bf16*)(S + 8388608);        // [4096][2048]  16.8 MB
  bf16* W2A = (bf16*)(S + 25165824);       // [1024][8192]  16.8 MB
  bf16* HTA = (bf16*)(S + 41943040);       // [2048][8192]  33.6 MB (end 75.5)
  // expert phase
  bf16* EW1T = (bf16*)S;                   // 4x[4096][1024] 33.6 MB
  bf16* HE   = (bf16*)(S + 33554432);      // 4x[2048][4096] 67.1 MB
  bf16* EW2T = (bf16*)(S + 100663296);     // 4x[1024][4096] 33.6 MB
  // logits phase
  bf16* WLT  = (bf16*)S;                   // [32000][1024]  65.5 MB

  embed_kernel<<<dim3(Tm), dim3(256), 0, stream>>>(ids, emb, X);

  // ---- temporal residual MLP blocks: augmented-K GEMMs ([h|l] storage) ----
  for (int l = 0; l < 2; ++l) {
    transpose_cvt<true><<<dim3(DFFm / 64, Dm / 64, 1), dim3(16, 16), 0, stream>>>(
        tw1 + (long)l * Dm * DFFm, W1A, Dm, DFFm, 0, 0);
    transpose_cvt<true><<<dim3(Dm / 64, DFFm / 64, 1), dim3(16, 16), 0, stream>>>(
        tw2 + (long)l * DFFm * Dm, W2A, DFFm, Dm, 0, 0);
    ln_aug2_kernel<<<dim3(Tm), dim3(256), 0, stream>>>(X, tlns + l * Dm, tlnb + l * Dm, A1);

    // virtual K=3072: A [h|l|h] (phys [h|l], aT=2048,aS2=2048),
    //                 B [h|h|l] (phys [h|l], bT=1024,bS2=1024)
    GemmP p1{};
    p1.Ah = A1; p1.Bh = W1A;
    p1.bias = tb1 + (long)l * DFFm;
    p1.outH = HTA;
    p1.K = 3072; p1.N = DFFm; p1.lda = 2048; p1.ldb = 2048; p1.ldo = 2 * DFFm;
    p1.aT = 2048; p1.aS2 = 2048; p1.bT = 1024; p1.bS2 = 1024;
    gemm_bt<EPI_GELU_SPLIT, false, true>
        <<<dim3(DFFm / 128, Tm / 128, 1), dim3(256), 0, stream>>>(p1);

    // virtual K=12288 split-K 8: A [h|l|h] (phys 8192, aT=8192,aS2=8192),
    //                            B [h|h|l] (phys 8192, bT=4096,bS2=4096)
    GemmP p2{};
    p2.Ah = HTA; p2.Bh = W2A;
    p2.bias = tb2 + (long)l * Dm;
    p2.outF = X;                         // X pre-holds residual; chunks atomicAdd
    p2.K = 1536; p2.N = Dm; p2.lda = 8192; p2.ldb = 8192;
    p2.kcShift = 3; p2.kcK = 1536;
    p2.aT = 8192; p2.aS2 = 8192; p2.bT = 4096; p2.bS2 = 4096;
    gemm_bt<EPI_RESID, false, true>
        <<<dim3(Dm / 128, Tm / 128, 8), dim3(256), 0, stream>>>(p2);
  }

  // ---- router (fp32) fused with token lists + XB convert ----
  hipMemsetAsync(cnt, 0, 8 * 4, stream);
  router_kernel<<<dim3(Tm), dim3(64), 0, stream>>>(X, Wr, br, rwout, XB, cnt, idxl);
  hipMemsetAsync(Y, 0, (size_t)Tm * Dm * 4, stream);

  // ---- sparse top-2 expert stack, 2 quads of 4 experts (bf16, 128^2) ----
  for (int q = 0; q < 2; ++q) {
    transpose_cvt<false><<<dim3(DFFm / 64, Dm / 64, 4), dim3(16, 16), 0, stream>>>(
        ew1 + (long)q * 4 * Dm * DFFm, EW1T, Dm, DFFm, (long)Dm * DFFm, (long)DFFm * Dm);
    transpose_cvt<false><<<dim3(Dm / 64, DFFm / 64, 4), dim3(16, 16), 0, stream>>>(
        ew2 + (long)q * 4 * DFFm * Dm, EW2T, DFFm, Dm, (long)DFFm * Dm, (long)Dm * DFFm);

    GemmP pe1{};
    pe1.Ah = XB; pe1.Bh = EW1T;
    pe1.bias = eb1 + (long)q * 4 * DFFm; pe1.biasBS = DFFm;
    pe1.outH = HE; pe1.outBS = (long)Tm * DFFm;
    pe1.aBS = 0; pe1.bBS = (long)DFFm * Dm;
    pe1.cnt = cnt; pe1.idx = idxl; pe1.ebase = q * 4;
    pe1.K = Dm; pe1.N = DFFm; pe1.lda = Dm; pe1.ldb = Dm;
    gemm_bt<EPI_GELU_BF16, true, true>
        <<<dim3(DFFm / 128, Tm / 128, 4), dim3(256), 0, stream>>>(pe1);

    GemmP pe2{};
    pe2.Ah = HE; pe2.aBS = (long)Tm * DFFm;
    pe2.Bh = EW2T; pe2.bBS = (long)Dm * DFFm;
    pe2.bias = eb2 + (long)q * 4 * Dm; pe2.biasBS = Dm;
    pe2.rwp = rwout; pe2.cnt = cnt; pe2.idx = idxl; pe2.ebase = q * 4;
    pe2.outF = Y;
    pe2.K = 1024; pe2.N = Dm; pe2.lda = DFFm; pe2.ldb = DFFm;
    pe2.kcShift = 2; pe2.kcK = 1024;
    gemm_bt<EPI_MOE, false, true>
        <<<dim3(Dm / 128, Tm / 128, 16), dim3(256), 0, stream>>>(pe2);
  }

  // ---- final logits GEMM: 256^2 8-phase counted-vmcnt pipeline ----
  cvt_bf16_kernel<<<dim3(Tm * Dm / (256 * 8)), dim3(256), 0, stream>>>(Y, YB, (long)Tm * Dm);
  transpose_cvt<false><<<dim3(Vm / 64, Dm / 64, 1), dim3(16, 16), 0, stream>>>(
      Wl, WLT, Dm, Vm, 0, 0);
  gemm256_8p<true><<<dim3(Vm / 256, Tm / 256, 1), dim3(512), 0, stream>>>(
      YB, WLT, bl, logits, Dm, Vm);
}